// Round 5
// baseline (288.450 us; speedup 1.0000x reference)
//
#include <hip/hip_runtime.h>
#include <math.h>

#define N_NODES   16000
#define N_EDGES   512000
#define EMBED_DIM 28
#define NODE_DIM  128
#define NUM_BASIS 20

// rsh_kernel: RSH_BLOCKS*256 threads; thread owns fixed float4-column c of a
// 120-f4 row, strides over edges. ROWSTRIDE divides N_EDGES exactly:
// 512000 / 4000 = 128 iterations = 32 x 4-unrolled.
#define RSH_BLOCKS    1875
#define RSH_THREADS   (RSH_BLOCKS * 256)          // 480000
#define RSH_ROWSTRIDE (RSH_THREADS / 120)         // 4000
#define RSH_ITERS     (N_EDGES / RSH_ROWSTRIDE)   // 128

typedef float f32x4 __attribute__((ext_vector_type(4)));

// ---------------------------------------------------------------------------
// x_scalar[node][d] = dot(embed_table[at_no[node]], W[d]) + b[d]
// ---------------------------------------------------------------------------
__global__ __launch_bounds__(256) void node_kernel(
    const int*   __restrict__ at_no,
    const float* __restrict__ embed,
    const float* __restrict__ W,
    const float* __restrict__ b,
    float*       __restrict__ out)
{
    int idx = blockIdx.x * 256 + threadIdx.x;
    if (idx >= N_NODES * NODE_DIM) return;
    int node = idx >> 7;
    int d    = idx & 127;
    int a    = at_no[node];
    const float* er = embed + a * EMBED_DIM;
    const float* wr = W + d * EMBED_DIM;
    float sum = b[d];
#pragma unroll
    for (int k = 0; k < EMBED_DIM; ++k)
        sum = fmaf(er[k], wr[k], sum);
    __builtin_nontemporal_store(sum, out + idx);
}

// ---------------------------------------------------------------------------
// Kernel A: one thread per edge. dist -> fcut, rbf (sin recurrence),
// shv12[12] = [1.0, S3ux, S3uy, S3uz, t0, t1, t2, t3, t4, 0, 0, 0]
// shv12 written with REGULAR stores (we want it L2-resident for kernel B).
// ---------------------------------------------------------------------------
__global__ __launch_bounds__(256) void edge_scalar_kernel(
    const float* __restrict__ pos,
    const int*   __restrict__ eidx,
    float*       __restrict__ rbf,
    float*       __restrict__ fcut,
    float4*      __restrict__ shv12)   // 3 float4 per edge
{
    int e = blockIdx.x * 256 + threadIdx.x;
    if (e >= N_EDGES) return;
    int s  = eidx[e];
    int dn = eidx[N_EDGES + e];

    // reference permutes pos columns by [1,2,0]
    float ax = pos[s*3+1],  ay = pos[s*3+2],  az = pos[s*3+0];
    float bx = pos[dn*3+1], by = pos[dn*3+2], bz = pos[dn*3+0];
    float vx = ax - bx, vy = ay - by, vz = az - bz;
    float dist = sqrtf(vx*vx + vy*vy + vz*vz);
    float inv  = 1.0f / dist;
    float ux = vx*inv, uy = vy*inv, uz = vz*inv;

    const float S3  = 1.7320508075688772f;
    const float S5  = 2.2360679774997896f;
    const float S15 = 3.8729833462074170f;
    float t0 = S15 * ux * uz;
    float t1 = S15 * ux * uy;
    float t2 = S5  * (uy*uy - 0.5f*(ux*ux + uz*uz));
    float t3 = S15 * uy * uz;
    float t4 = 0.5f * S15 * (uz*uz - ux*ux);

    shv12[3*e]   = make_float4(1.0f, S3*ux, S3*uy, S3*uz);
    shv12[3*e+1] = make_float4(t0, t1, t2, t3);
    shv12[3*e+2] = make_float4(t4, 0.0f, 0.0f, 0.0f);

    // cutoff poly p=5: 1 - 21u^5 + 35u^6 - 15u^7
    float u  = dist * 0.2f;
    float u2 = u*u, u5 = u2*u2*u;
    float f  = 1.0f + u5*(-21.0f + u*(35.0f - 15.0f*u));
    __builtin_nontemporal_store((u < 1.0f) ? f : 0.0f, fcut + e);

    // rbf[n] = sqrt(2/5) * sin(n*pi*dist/5) / dist, n=1..20 via recurrence
    float th = 0.62831853071795864769f * dist;   // pi/5 * dist
    float s1 = __sinf(th), c1 = __cosf(th);
    float twoc = 2.0f * c1;
    float k = 0.6324555320336759f * inv;
    float sp = 0.0f, sc = s1;
    f32x4 r[5];
#pragma unroll
    for (int q = 0; q < 5; ++q) {
        float v0 = k * sc; float nx;
        nx = twoc*sc - sp; sp = sc; sc = nx; float v1 = k*sc;
        nx = twoc*sc - sp; sp = sc; sc = nx; float v2 = k*sc;
        nx = twoc*sc - sp; sp = sc; sc = nx; float v3 = k*sc;
        nx = twoc*sc - sp; sp = sc; sc = nx;
        f32x4 t; t.x = v0; t.y = v1; t.z = v2; t.w = v3;
        r[q] = t;
    }
    f32x4* ro = (f32x4*)(rbf + (size_t)e * NUM_BASIS);
#pragma unroll
    for (int q = 0; q < 5; ++q)
        __builtin_nontemporal_store(r[q], ro + q);
}

// ---------------------------------------------------------------------------
// Kernel B: streaming writer for rsh. Per-thread selectors j0..j3 are
// loop-invariant; 4-way unrolled with independent pointers for MLP.
// ---------------------------------------------------------------------------
__global__ __launch_bounds__(256) void rsh_kernel(
    const float* __restrict__ shv12,
    float*       __restrict__ rsh)
{
    int g    = blockIdx.x * 256 + threadIdx.x;
    int row0 = g / 120;
    int c    = g - row0 * 120;

    // selector for component k of float4 slot c (column = 4c+k):
    //   col < 128          -> 0          (the 1.0 slot)
    //   128 <= col < 320   -> 1 + (col-128)%3
    //   col >= 320         -> 4 + (col-320)%5
    int j[4];
#pragma unroll
    for (int k = 0; k < 4; ++k) {
        int col = 4 * c + k;
        int jj;
        if (col < 128)      jj = 0;
        else if (col < 320) jj = 1 + (col - 128) % 3;
        else                jj = 4 + (col - 320) % 5;
        j[k] = jj;
    }
    const int j0 = j[0], j1 = j[1], j2 = j[2], j3 = j[3];

    const int    bstep = 12 * RSH_ROWSTRIDE;            // floats
    const size_t ostep = (size_t)480 * RSH_ROWSTRIDE;   // floats

    const float* b0 = shv12 + 12 * row0;
    const float* b1 = b0 + bstep;
    const float* b2 = b1 + bstep;
    const float* b3 = b2 + bstep;
    float* o0 = rsh + (size_t)row0 * 480 + 4 * c;
    float* o1 = o0 + ostep;
    float* o2 = o1 + ostep;
    float* o3 = o2 + ostep;

#pragma unroll 1
    for (int it = 0; it < RSH_ITERS / 4; ++it) {
        f32x4 v0, v1, v2, v3;
        v0.x = b0[j0]; v0.y = b0[j1]; v0.z = b0[j2]; v0.w = b0[j3];
        v1.x = b1[j0]; v1.y = b1[j1]; v1.z = b1[j2]; v1.w = b1[j3];
        v2.x = b2[j0]; v2.y = b2[j1]; v2.z = b2[j2]; v2.w = b2[j3];
        v3.x = b3[j0]; v3.y = b3[j1]; v3.z = b3[j2]; v3.w = b3[j3];
        __builtin_nontemporal_store(v0, (f32x4*)o0);
        __builtin_nontemporal_store(v1, (f32x4*)o1);
        __builtin_nontemporal_store(v2, (f32x4*)o2);
        __builtin_nontemporal_store(v3, (f32x4*)o3);
        b0 += 4 * bstep; b1 += 4 * bstep; b2 += 4 * bstep; b3 += 4 * bstep;
        o0 += 4 * ostep; o1 += 4 * ostep; o2 += 4 * ostep; o3 += 4 * ostep;
    }
}

// ---------------------------------------------------------------------------
// Fallback (round-1 structure) if ws is too small for shv12.
// ---------------------------------------------------------------------------
__global__ __launch_bounds__(256) void edge_kernel_fb(
    const float* __restrict__ pos,
    const int*   __restrict__ eidx,
    float*       __restrict__ rbf,
    float*       __restrict__ fcut,
    float*       __restrict__ rsh)
{
    const int sub = threadIdx.x >> 7;
    const int t   = threadIdx.x & 127;
    const int e   = blockIdx.x * 2 + sub;

    int s  = eidx[e];
    int dn = eidx[N_EDGES + e];
    float ax = pos[s*3+1],  ay = pos[s*3+2],  az = pos[s*3+0];
    float bx = pos[dn*3+1], by = pos[dn*3+2], bz = pos[dn*3+0];
    float vx = ax - bx, vy = ay - by, vz = az - bz;
    float dist = sqrtf(vx*vx + vy*vy + vz*vz);
    float inv  = 1.0f / dist;
    float ux = vx*inv, uy = vy*inv, uz = vz*inv;

    const float S3  = 1.7320508075688772f;
    const float S5  = 2.2360679774997896f;
    const float S15 = 3.8729833462074170f;

    __shared__ float shv[2][8];
    if (t == 0) {
        shv[sub][0] = S3 * ux;  shv[sub][1] = S3 * uy;  shv[sub][2] = S3 * uz;
        shv[sub][3] = S15 * ux * uz;  shv[sub][4] = S15 * ux * uy;
        shv[sub][5] = S5  * (uy*uy - 0.5f*(ux*ux + uz*uz));
        shv[sub][6] = S15 * uy * uz;
        shv[sub][7] = 0.5f * S15 * (uz*uz - ux*ux);
    }
    __syncthreads();

    if (t < NUM_BASIS) {
        float arg = (float)(t + 1) * 0.62831853071795864769f * dist;
        rbf[e * NUM_BASIS + t] = 0.6324555320336759f * __sinf(arg) * inv;
    } else if (t == NUM_BASIS) {
        float u  = dist * 0.2f;
        float u2 = u * u, u5 = u2 * u2 * u;
        float f  = 1.0f + u5 * (-21.0f + u * (35.0f - 15.0f * u));
        fcut[e] = (u < 1.0f) ? f : 0.0f;
    }
    if (t < 120) {
        int c0 = 4 * t;
        float4 v;
        if (c0 < 128) v = make_float4(1.0f, 1.0f, 1.0f, 1.0f);
        else if (c0 < 320) {
            int r = (c0 - 128) % 3;
            v.x = shv[sub][r]; v.y = shv[sub][(r+1)%3];
            v.z = shv[sub][(r+2)%3]; v.w = shv[sub][r];
        } else {
            int r = (c0 - 320) % 5;
            v.x = shv[sub][3 + r];         v.y = shv[sub][3 + (r+1)%5];
            v.z = shv[sub][3 + (r+2)%5];   v.w = shv[sub][3 + (r+3)%5];
        }
        reinterpret_cast<float4*>(rsh + (size_t)e * 480)[t] = v;
    }
}

extern "C" void kernel_launch(void* const* d_in, const int* in_sizes, int n_in,
                              void* d_out, int out_size, void* d_ws, size_t ws_size,
                              hipStream_t stream) {
    const int*   at_no = (const int*)  d_in[0];
    const float* pos   = (const float*)d_in[1];
    const int*   eidx  = (const int*)  d_in[2];
    const float* embed = (const float*)d_in[3];
    const float* W     = (const float*)d_in[4];
    const float* b     = (const float*)d_in[5];

    float* out      = (float*)d_out;
    float* x_scalar = out;                                   // 16000*128
    float* rbf      = x_scalar + (size_t)N_NODES * NODE_DIM; // 512000*20
    float* fcut     = rbf + (size_t)N_EDGES * NUM_BASIS;     // 512000
    float* rsh      = fcut + N_EDGES;                        // 512000*480

    node_kernel<<<(N_NODES * NODE_DIM + 255) / 256, 256, 0, stream>>>(
        at_no, embed, W, b, x_scalar);

    const size_t shv_bytes = (size_t)N_EDGES * 12 * sizeof(float);
    if (ws_size >= shv_bytes) {
        float4* shv12 = (float4*)d_ws;
        edge_scalar_kernel<<<(N_EDGES + 255) / 256, 256, 0, stream>>>(
            pos, eidx, rbf, fcut, shv12);
        rsh_kernel<<<RSH_BLOCKS, 256, 0, stream>>>((const float*)d_ws, rsh);
    } else {
        edge_kernel_fb<<<N_EDGES / 2, 256, 0, stream>>>(
            pos, eidx, rbf, fcut, rsh);
    }
}

// Round 6
// 230.705 us; speedup vs baseline: 1.2503x; 1.2503x over previous
//
#include <hip/hip_runtime.h>
#include <math.h>

#define N_NODES   16000
#define N_EDGES   512000
#define EMBED_DIM 28
#define NODE_DIM  128
#define NUM_BASIS 20

#define EPB  256                    // edges per block
#define NBLK (N_EDGES / EPB)        // 2000 blocks, exact

typedef float f32x4 __attribute__((ext_vector_type(4)));

// ---------------------------------------------------------------------------
// x_scalar[node][d] = dot(embed_table[at_no[node]], W[d]) + b[d]
// ---------------------------------------------------------------------------
__global__ __launch_bounds__(256) void node_kernel(
    const int*   __restrict__ at_no,
    const float* __restrict__ embed,
    const float* __restrict__ W,
    const float* __restrict__ b,
    float*       __restrict__ out)
{
    int idx = blockIdx.x * 256 + threadIdx.x;
    if (idx >= N_NODES * NODE_DIM) return;
    int node = idx >> 7;
    int d    = idx & 127;
    int a    = at_no[node];
    const float* er = embed + a * EMBED_DIM;
    const float* wr = W + d * EMBED_DIM;
    float sum = b[d];
#pragma unroll
    for (int k = 0; k < EMBED_DIM; ++k)
        sum = fmaf(er[k], wr[k], sum);
    __builtin_nontemporal_store(sum, out + idx);
}

// ---------------------------------------------------------------------------
// Fused edge kernel. Block owns 256 consecutive edges.
// Phase 1: per-thread edge compute -> fcut (direct), rbf -> LDS, shv -> LDS.
// Phase 2: coalesced rbf writeout.
// Phase 3: 120 iterations of LDS-gather -> contiguous nt dwordx4 store.
// ---------------------------------------------------------------------------
__global__ __launch_bounds__(256) void fused_edge_kernel(
    const float* __restrict__ pos,
    const int*   __restrict__ eidx,
    float*       __restrict__ rbf,
    float*       __restrict__ fcut,
    float*       __restrict__ rsh)
{
    __shared__ float    sh_shv[EPB * 12];   // 12 KB: [edge][12] rows
    __shared__ float    sh_rbf[EPB * 20];   // 20 KB
    __shared__ unsigned sh_sel[120];        // packed byte-offset selectors

    const int t  = threadIdx.x;
    const int e0 = blockIdx.x * EPB;
    const int e  = e0 + t;

    // Selector table: float4 slot c covers columns 4c..4c+3 of the 480 row.
    //   col < 128          -> shv slot 0 (the 1.0)
    //   128 <= col < 320   -> 1 + (col-128)%3
    //   col >= 320         -> 4 + (col-320)%5
    // packed as byte offsets (j*4) into the 12-float row.
    if (t < 120) {
        unsigned pack = 0;
#pragma unroll
        for (int k = 0; k < 4; ++k) {
            int col = 4 * t + k;
            int jj;
            if (col < 128)      jj = 0;
            else if (col < 320) jj = 1 + (col - 128) % 3;
            else                jj = 4 + (col - 320) % 5;
            pack |= (unsigned)(jj * 4) << (8 * k);
        }
        sh_sel[t] = pack;
    }

    // ---- Phase 1: edge compute ----
    {
        int s  = eidx[e];
        int dn = eidx[N_EDGES + e];

        // reference permutes pos columns by [1,2,0]
        float ax = pos[s*3+1],  ay = pos[s*3+2],  az = pos[s*3+0];
        float bx = pos[dn*3+1], by = pos[dn*3+2], bz = pos[dn*3+0];
        float vx = ax - bx, vy = ay - by, vz = az - bz;
        float dist = sqrtf(vx*vx + vy*vy + vz*vz);
        float inv  = 1.0f / dist;
        float ux = vx*inv, uy = vy*inv, uz = vz*inv;

        const float S3  = 1.7320508075688772f;
        const float S5  = 2.2360679774997896f;
        const float S15 = 3.8729833462074170f;

        float* r = sh_shv + t * 12;
        r[0] = 1.0f;
        r[1] = S3 * ux;  r[2] = S3 * uy;  r[3] = S3 * uz;
        r[4] = S15 * ux * uz;
        r[5] = S15 * ux * uy;
        r[6] = S5  * (uy*uy - 0.5f*(ux*ux + uz*uz));
        r[7] = S15 * uy * uz;
        r[8] = 0.5f * S15 * (uz*uz - ux*ux);

        // cutoff poly p=5: 1 - 21u^5 + 35u^6 - 15u^7
        float u  = dist * 0.2f;
        float u2 = u*u, u5 = u2*u2*u;
        float f  = 1.0f + u5*(-21.0f + u*(35.0f - 15.0f*u));
        __builtin_nontemporal_store((u < 1.0f) ? f : 0.0f, fcut + e);

        // rbf[n] = sqrt(2/5) * sin(n*pi*dist/5)/dist via Chebyshev recurrence
        float th = 0.62831853071795864769f * dist;   // pi/5 * dist
        float s1 = __sinf(th), c1 = __cosf(th);
        float twoc = 2.0f * c1;
        float kk = 0.6324555320336759f * inv;
        float sp = 0.0f, sc = s1;
        float* rb = sh_rbf + t * 20;
#pragma unroll
        for (int q = 0; q < NUM_BASIS; ++q) {
            rb[q] = kk * sc;
            float nx = twoc*sc - sp; sp = sc; sc = nx;
        }
    }
    __syncthreads();

    // ---- Phase 2: coalesced rbf writeout (5 x 256 float4) ----
    {
        const f32x4* ls = (const f32x4*)sh_rbf;
        f32x4* go = (f32x4*)(rbf + (size_t)e0 * NUM_BASIS);
#pragma unroll
        for (int q = 0; q < 5; ++q)
            __builtin_nontemporal_store(ls[q * EPB + t], go + q * EPB + t);
    }

    // ---- Phase 3: rsh stream. slot g = i*256 + t, row le = g/120, col c ----
    {
        int le = t / 120;
        int c  = t - le * 120;
        float* outp = rsh + (size_t)e0 * 480 + (size_t)t * 4;

#pragma unroll 2
        for (int i = 0; i < 120; ++i) {
            unsigned pk = sh_sel[c];
            const char* row = (const char*)(sh_shv + le * 12);
            f32x4 v;
            v.x = *(const float*)(row + (pk & 0xffu));
            v.y = *(const float*)(row + ((pk >> 8) & 0xffu));
            v.z = *(const float*)(row + ((pk >> 16) & 0xffu));
            v.w = *(const float*)(row + (pk >> 24));
            __builtin_nontemporal_store(v, (f32x4*)outp);
            outp += 256 * 4;            // next 256 float4 slots
            c += 16; le += 2;
            if (c >= 120) { c -= 120; le += 1; }
        }
    }
}

extern "C" void kernel_launch(void* const* d_in, const int* in_sizes, int n_in,
                              void* d_out, int out_size, void* d_ws, size_t ws_size,
                              hipStream_t stream) {
    const int*   at_no = (const int*)  d_in[0];
    const float* pos   = (const float*)d_in[1];
    const int*   eidx  = (const int*)  d_in[2];
    const float* embed = (const float*)d_in[3];
    const float* W     = (const float*)d_in[4];
    const float* b     = (const float*)d_in[5];

    float* out      = (float*)d_out;
    float* x_scalar = out;                                   // 16000*128
    float* rbf      = x_scalar + (size_t)N_NODES * NODE_DIM; // 512000*20
    float* fcut     = rbf + (size_t)N_EDGES * NUM_BASIS;     // 512000
    float* rsh      = fcut + N_EDGES;                        // 512000*480

    node_kernel<<<(N_NODES * NODE_DIM + 255) / 256, 256, 0, stream>>>(
        at_no, embed, W, b, x_scalar);

    fused_edge_kernel<<<NBLK, 256, 0, stream>>>(
        pos, eidx, rbf, fcut, rsh);
}

// Round 7
// 216.422 us; speedup vs baseline: 1.3328x; 1.0660x over previous
//
#include <hip/hip_runtime.h>
#include <math.h>

#define N_NODES   16000
#define N_EDGES   512000
#define EMBED_DIM 28
#define NODE_DIM  128
#define NUM_BASIS 20

#define EPB  256                    // edges per block
#define NBLK (N_EDGES / EPB)        // 2000 blocks, exact

typedef float f32x4 __attribute__((ext_vector_type(4)));

// ---------------------------------------------------------------------------
// x_scalar[node][d] = dot(embed_table[at_no[node]], W[d]) + b[d]
// ---------------------------------------------------------------------------
__global__ __launch_bounds__(256) void node_kernel(
    const int*   __restrict__ at_no,
    const float* __restrict__ embed,
    const float* __restrict__ W,
    const float* __restrict__ b,
    float*       __restrict__ out)
{
    int idx = blockIdx.x * 256 + threadIdx.x;
    if (idx >= N_NODES * NODE_DIM) return;
    int node = idx >> 7;
    int d    = idx & 127;
    int a    = at_no[node];
    const float* er = embed + a * EMBED_DIM;
    const float* wr = W + d * EMBED_DIM;
    float sum = b[d];
#pragma unroll
    for (int k = 0; k < EMBED_DIM; ++k)
        sum = fmaf(er[k], wr[k], sum);
    out[idx] = sum;
}

// ---------------------------------------------------------------------------
// Fused edge kernel. Block owns 256 consecutive edges.
// Phase 1: per-thread edge compute -> fcut (direct), rbf -> LDS, shv -> LDS.
// Phase 2: coalesced rbf writeout.
// Phase 3: 120 iterations of LDS-gather -> contiguous dwordx4 store.
// All stores REGULAR (cached) — A/B vs round 6's nontemporal.
// ---------------------------------------------------------------------------
__global__ __launch_bounds__(256) void fused_edge_kernel(
    const float* __restrict__ pos,
    const int*   __restrict__ eidx,
    float*       __restrict__ rbf,
    float*       __restrict__ fcut,
    float*       __restrict__ rsh)
{
    __shared__ float    sh_shv[EPB * 12];   // 12 KB: [edge][12] rows
    __shared__ float    sh_rbf[EPB * 20];   // 20 KB
    __shared__ unsigned sh_sel[120];        // packed byte-offset selectors

    const int t  = threadIdx.x;
    const int e0 = blockIdx.x * EPB;
    const int e  = e0 + t;

    // Selector table: float4 slot c covers columns 4c..4c+3 of the 480 row.
    //   col < 128          -> shv slot 0 (the 1.0)
    //   128 <= col < 320   -> 1 + (col-128)%3
    //   col >= 320         -> 4 + (col-320)%5
    // packed as byte offsets (j*4) into the 12-float row.
    if (t < 120) {
        unsigned pack = 0;
#pragma unroll
        for (int k = 0; k < 4; ++k) {
            int col = 4 * t + k;
            int jj;
            if (col < 128)      jj = 0;
            else if (col < 320) jj = 1 + (col - 128) % 3;
            else                jj = 4 + (col - 320) % 5;
            pack |= (unsigned)(jj * 4) << (8 * k);
        }
        sh_sel[t] = pack;
    }

    // ---- Phase 1: edge compute ----
    {
        int s  = eidx[e];
        int dn = eidx[N_EDGES + e];

        // reference permutes pos columns by [1,2,0]
        float ax = pos[s*3+1],  ay = pos[s*3+2],  az = pos[s*3+0];
        float bx = pos[dn*3+1], by = pos[dn*3+2], bz = pos[dn*3+0];
        float vx = ax - bx, vy = ay - by, vz = az - bz;
        float dist = sqrtf(vx*vx + vy*vy + vz*vz);
        float inv  = 1.0f / dist;
        float ux = vx*inv, uy = vy*inv, uz = vz*inv;

        const float S3  = 1.7320508075688772f;
        const float S5  = 2.2360679774997896f;
        const float S15 = 3.8729833462074170f;

        float* r = sh_shv + t * 12;
        r[0] = 1.0f;
        r[1] = S3 * ux;  r[2] = S3 * uy;  r[3] = S3 * uz;
        r[4] = S15 * ux * uz;
        r[5] = S15 * ux * uy;
        r[6] = S5  * (uy*uy - 0.5f*(ux*ux + uz*uz));
        r[7] = S15 * uy * uz;
        r[8] = 0.5f * S15 * (uz*uz - ux*ux);

        // cutoff poly p=5: 1 - 21u^5 + 35u^6 - 15u^7
        float u  = dist * 0.2f;
        float u2 = u*u, u5 = u2*u2*u;
        float f  = 1.0f + u5*(-21.0f + u*(35.0f - 15.0f*u));
        fcut[e] = (u < 1.0f) ? f : 0.0f;

        // rbf[n] = sqrt(2/5) * sin(n*pi*dist/5)/dist via Chebyshev recurrence
        float th = 0.62831853071795864769f * dist;   // pi/5 * dist
        float s1 = __sinf(th), c1 = __cosf(th);
        float twoc = 2.0f * c1;
        float kk = 0.6324555320336759f * inv;
        float sp = 0.0f, sc = s1;
        float* rb = sh_rbf + t * 20;
#pragma unroll
        for (int q = 0; q < NUM_BASIS; ++q) {
            rb[q] = kk * sc;
            float nx = twoc*sc - sp; sp = sc; sc = nx;
        }
    }
    __syncthreads();

    // ---- Phase 2: coalesced rbf writeout (5 x 256 float4) ----
    {
        const f32x4* ls = (const f32x4*)sh_rbf;
        f32x4* go = (f32x4*)(rbf + (size_t)e0 * NUM_BASIS);
#pragma unroll
        for (int q = 0; q < 5; ++q)
            go[q * EPB + t] = ls[q * EPB + t];
    }

    // ---- Phase 3: rsh stream. slot g = i*256 + t, row le = g/120, col c ----
    {
        int le = t / 120;
        int c  = t - le * 120;
        float* outp = rsh + (size_t)e0 * 480 + (size_t)t * 4;

#pragma unroll 2
        for (int i = 0; i < 120; ++i) {
            unsigned pk = sh_sel[c];
            const char* row = (const char*)(sh_shv + le * 12);
            f32x4 v;
            v.x = *(const float*)(row + (pk & 0xffu));
            v.y = *(const float*)(row + ((pk >> 8) & 0xffu));
            v.z = *(const float*)(row + ((pk >> 16) & 0xffu));
            v.w = *(const float*)(row + (pk >> 24));
            *(f32x4*)outp = v;
            outp += 256 * 4;            // next 256 float4 slots
            c += 16; le += 2;
            if (c >= 120) { c -= 120; le += 1; }
        }
    }
}

extern "C" void kernel_launch(void* const* d_in, const int* in_sizes, int n_in,
                              void* d_out, int out_size, void* d_ws, size_t ws_size,
                              hipStream_t stream) {
    const int*   at_no = (const int*)  d_in[0];
    const float* pos   = (const float*)d_in[1];
    const int*   eidx  = (const int*)  d_in[2];
    const float* embed = (const float*)d_in[3];
    const float* W     = (const float*)d_in[4];
    const float* b     = (const float*)d_in[5];

    float* out      = (float*)d_out;
    float* x_scalar = out;                                   // 16000*128
    float* rbf      = x_scalar + (size_t)N_NODES * NODE_DIM; // 512000*20
    float* fcut     = rbf + (size_t)N_EDGES * NUM_BASIS;     // 512000
    float* rsh      = fcut + N_EDGES;                        // 512000*480

    node_kernel<<<(N_NODES * NODE_DIM + 255) / 256, 256, 0, stream>>>(
        at_no, embed, W, b, x_scalar);

    fused_edge_kernel<<<NBLK, 256, 0, stream>>>(
        pos, eidx, rbf, fcut, rsh);
}